// Round 5
// baseline (8721.738 us; speedup 1.0000x reference)
//
#include <hip/hip_runtime.h>
#include <hip/hip_bf16.h>

#define NA 50000
#define NPAP 100000
#define DIN 512
#define DHID 512
#define DOUT 256
#define EAP 400000
#define EPA 400000
#define EAA 200000

typedef unsigned short u16;
typedef __attribute__((ext_vector_type(8))) short bf16x8;
typedef __attribute__((ext_vector_type(4))) float f32x4;

// ---------------- utility kernels ----------------

__global__ void fill_u32_kernel(unsigned* __restrict__ p, unsigned v, int n) {
    int i = blockIdx.x * blockDim.x + threadIdx.x;
    if (i < n) p[i] = v;
}

__global__ void copy_i32_kernel(const int* __restrict__ a, int* __restrict__ b, int n) {
    int i = blockIdx.x * blockDim.x + threadIdx.x;
    if (i < n) b[i] = a[i];
}

// Detect whether edge arrays are int64 (high word of every pair-slot zero) or int32.
__global__ void detect_kernel(const unsigned* __restrict__ e, int npairs, int* __restrict__ flag) {
    __shared__ int anyn;
    if (threadIdx.x == 0) anyn = 0;
    __syncthreads();
    unsigned local = 0;
    for (int i = threadIdx.x; i < npairs; i += blockDim.x) local |= e[2 * i + 1];
    if (local) atomicOr(&anyn, 1);
    __syncthreads();
    if (threadIdx.x == 0) flag[0] = (anyn == 0) ? 1 : 0;
}

__device__ inline int edge_at(const void* e, size_t idx, int i64) {
    return i64 ? (int)((const long long*)e)[idx] : ((const int*)e)[idx];
}

__device__ inline unsigned f2mono(float f) {
    unsigned u = __float_as_uint(f);
    return (u & 0x80000000u) ? ~u : (u | 0x80000000u);
}
__device__ inline float mono2f(unsigned u) {
    unsigned b = (u & 0x80000000u) ? (u ^ 0x80000000u) : ~u;
    return __uint_as_float(b);
}
#define MONO_NEG_INF 0x007FFFFFu  // f2mono(-inf)

// ---------------- B transpose + bf16 hi/lo split, GEMM-tile swizzled layout -------
// B: [K,N] f32 row-major. Output planes bth/btl laid out as
// [nblk][kblk][row 0..127][chunk 0..3][8 u16], where physical chunk p of row r
// holds logical k-chunk (p ^ ((r>>1)&3)).  This matches the GEMM's LDS tile
// byte-for-byte, so staging is a plain linear copy (conflict-free) and the
// swizzled ds_read is conflict-free too.

__global__ void conv_bt_kernel(const float* __restrict__ B, u16* __restrict__ bth,
                               u16* __restrict__ btl, int K, int N) {
    __shared__ float tile[32][33];
    const int nb = blockIdx.x * 32, kb = blockIdx.y * 32;
    const int tx = threadIdx.x, ty = threadIdx.y;
    const int KBLK = K >> 5;
    for (int i = ty; i < 32; i += 8)
        tile[i][tx] = B[(size_t)(kb + i) * N + nb + tx];
    __syncthreads();
    for (int i = ty; i < 32; i += 8) {
        float v = tile[tx][i];  // = B[kb+tx][nb+i] -> n = nb+i, k = kb+tx
        unsigned u = __float_as_uint(v);
        unsigned h = (u + 0x7FFFu + ((u >> 16) & 1u)) >> 16;  // RNE for hi
        float hf = __uint_as_float(h << 16);
        float r = v - hf;                                      // exact residual
        unsigned l = __float_as_uint(r) >> 16;                 // trunc for lo
        const int n = nb + i, k = kb + tx;
        const int nblk = n >> 7, row = n & 127;
        const int kblk = k >> 5, kc = (k & 31) >> 3, ke = k & 7;
        const int cph = kc ^ ((row >> 1) & 3);
        size_t o = (((size_t)(nblk * KBLK + kblk) * 128 + row) << 5) + (cph << 3) + ke;
        bth[o] = (u16)h;
        btl[o] = (u16)l;
    }
}

// ---------------- split-bf16 MFMA GEMM: C[M,N] = A[M,K] @ B[K,N] + bias ----------
// 256x128 tile, 512 threads (8 waves = 4M x 2N), single-buffered 48 KB LDS,
// 2-barrier loop -> 3 blocks/CU = 24 waves/CU. Global prefetch of tile t+1 is
// issued AFTER barrier2 so its latency hides under the MFMA phase of tile t.
// A fp32 reg-staged + split at store time; B copied linearly from pre-swizzled
// global tiles. 1-D grid with bijective XCD chunk swizzle.
// SCORE mode: atomicAdd(score, sum(tanh(C+bias)*q[col])).

template <bool SCORE>
__global__ __launch_bounds__(512, 6) void mfma_gemm_kernel(
    const float* __restrict__ A, const u16* __restrict__ Bth,
    const u16* __restrict__ Btl, const float* __restrict__ bias,
    float* __restrict__ C, int M, int N, int K,
    const float* __restrict__ qv, float* __restrict__ score, int gx)
{
    __shared__ u16 Ah[256][32];
    __shared__ u16 Al[256][32];
    __shared__ u16 Bh[128][32];
    __shared__ u16 Bl[128][32];

    // bijective XCD chunk remap (m204): XCD k processes a contiguous wg range.
    const int nwg = gridDim.x;
    const int bid = blockIdx.x;
    const int qc = nwg >> 3, rc = nwg & 7;
    const int xcd = bid & 7, idx = bid >> 3;
    const int wg = (xcd < rc ? xcd * (qc + 1) : rc * (qc + 1) + (xcd - rc) * qc) + idx;
    const int bx = wg % gx, by = wg / gx;
    const int m0 = by * 256;
    const int n0 = bx * 128;

    const int tid = threadIdx.x;
    const int lane = tid & 63;
    const int wv = tid >> 6;           // wave 0..7
    const int wm = wv >> 1, wn = wv & 1;
    const int fr = lane & 15;          // row/col within 16x16 fragment
    const int kg = lane >> 4;          // k-group 0..3

    // A staging: thread handles 16 consecutive K elems of one row (256 rows x 2)
    const int srow = tid >> 1;
    const int oh   = tid & 1;
    const bool a_ok = (m0 + srow) < M;
    const float* Ap = A + (size_t)(m0 + srow) * K + oh * 16;

    // swizzled LDS write positions for A (u16 units)
    const int swc = (srow >> 1) & 3;
    const int p0 = srow * 32 + ((((oh << 1) + 0) ^ swc) << 3);
    const int p1 = srow * 32 + ((((oh << 1) + 1) ^ swc) << 3);
    // swizzled read chunk (row bits 1..2 come from fr for all fragment rows)
    const int rdc = (kg ^ ((fr >> 1) & 3)) << 3;

    // B staging: linear copy, one uint4 per plane per thread (512 x 8 = 4096 u16)
    const int KBLK = K >> 5;
    const size_t btile0 = ((size_t)(n0 >> 7) * KBLK) << 12;  // *4096 u16 per tile
    const int bso = tid * 8;

    f32x4 acc[4][4] = {};
    float ar[16];
    uint4 rbh, rbl;

    auto load_ab = [&](int t) {
        const int k0 = t << 5;
        if (a_ok) {
            float4 v;
            v = *(const float4*)(Ap + k0);      ar[0]=v.x;  ar[1]=v.y;  ar[2]=v.z;  ar[3]=v.w;
            v = *(const float4*)(Ap + k0 + 4);  ar[4]=v.x;  ar[5]=v.y;  ar[6]=v.z;  ar[7]=v.w;
            v = *(const float4*)(Ap + k0 + 8);  ar[8]=v.x;  ar[9]=v.y;  ar[10]=v.z; ar[11]=v.w;
            v = *(const float4*)(Ap + k0 + 12); ar[12]=v.x; ar[13]=v.y; ar[14]=v.z; ar[15]=v.w;
        } else {
#pragma unroll
            for (int c = 0; c < 16; ++c) ar[c] = 0.f;
        }
        rbh = *(const uint4*)(Bth + btile0 + ((size_t)t << 12) + bso);
        rbl = *(const uint4*)(Btl + btile0 + ((size_t)t << 12) + bso);
    };

    auto store_ab = [&]() {
        unsigned hw[8], lw[8];
#pragma unroll
        for (int c = 0; c < 8; ++c) {
            // truncation split: a = hi + lo + eps, |eps| <= 2^-16 |a|
            unsigned u0 = __float_as_uint(ar[2 * c]);
            unsigned h0 = u0 >> 16;
            float r0 = ar[2 * c] - __uint_as_float(h0 << 16);
            unsigned l0 = __float_as_uint(r0) >> 16;
            unsigned u1 = __float_as_uint(ar[2 * c + 1]);
            unsigned h1 = u1 >> 16;
            float r1 = ar[2 * c + 1] - __uint_as_float(h1 << 16);
            unsigned l1 = __float_as_uint(r1) >> 16;
            hw[c] = h0 | (h1 << 16);
            lw[c] = l0 | (l1 << 16);
        }
        u16* ahp = &Ah[0][0];
        u16* alp = &Al[0][0];
        *(uint4*)&ahp[p0] = make_uint4(hw[0], hw[1], hw[2], hw[3]);
        *(uint4*)&ahp[p1] = make_uint4(hw[4], hw[5], hw[6], hw[7]);
        *(uint4*)&alp[p0] = make_uint4(lw[0], lw[1], lw[2], lw[3]);
        *(uint4*)&alp[p1] = make_uint4(lw[4], lw[5], lw[6], lw[7]);
        *(uint4*)&(&Bh[0][0])[bso] = rbh;
        *(uint4*)&(&Bl[0][0])[bso] = rbl;
    };

    load_ab(0);
    const int nt = K >> 5;
    for (int t = 0; t < nt; ++t) {
        __syncthreads();           // barrier 1: previous compute done reading LDS
        store_ab();                // tile t: regs -> LDS (waitcnt lands here)
        __syncthreads();           // barrier 2: stores visible
        if (t + 1 < nt) load_ab(t + 1);  // issue prefetch; hides under MFMA phase

        bf16x8 afh[4], afl[4], bfh[4], bfl[4];
#pragma unroll
        for (int i = 0; i < 4; ++i) {
            const int aoff = (wm * 64 + i * 16 + fr) * 32 + rdc;
            const int boff = (wn * 64 + i * 16 + fr) * 32 + rdc;
            afh[i] = *(const bf16x8*)&(&Ah[0][0])[aoff];
            afl[i] = *(const bf16x8*)&(&Al[0][0])[aoff];
            bfh[i] = *(const bf16x8*)&(&Bh[0][0])[boff];
            bfl[i] = *(const bf16x8*)&(&Bl[0][0])[boff];
        }
#pragma unroll
        for (int i = 0; i < 4; ++i)
#pragma unroll
            for (int j = 0; j < 4; ++j) {
                acc[i][j] = __builtin_amdgcn_mfma_f32_16x16x32_bf16(afh[i], bfh[j], acc[i][j], 0, 0, 0);
                acc[i][j] = __builtin_amdgcn_mfma_f32_16x16x32_bf16(afl[i], bfh[j], acc[i][j], 0, 0, 0);
                acc[i][j] = __builtin_amdgcn_mfma_f32_16x16x32_bf16(afh[i], bfl[j], acc[i][j], 0, 0, 0);
            }
    }

    // C/D layout (m89/m91-verified): col = lane&15, row = (lane>>4)*4 + reg
    if (!SCORE) {
#pragma unroll
        for (int j = 0; j < 4; ++j) {
            const int col = n0 + wn * 64 + j * 16 + fr;
            const float bj = bias[col];
#pragma unroll
            for (int i = 0; i < 4; ++i) {
                const int rbase = m0 + wm * 64 + i * 16 + kg * 4;
#pragma unroll
                for (int r = 0; r < 4; ++r) {
                    const int grow = rbase + r;
                    if (grow < M) C[(size_t)grow * N + col] = acc[i][j][r] + bj;
                }
            }
        }
    } else {
        float ssum = 0.f;
#pragma unroll
        for (int j = 0; j < 4; ++j) {
            const int col = n0 + wn * 64 + j * 16 + fr;
            const float bj = bias[col];
            const float qj = qv[col];
#pragma unroll
            for (int i = 0; i < 4; ++i) {
                const int rbase = m0 + wm * 64 + i * 16 + kg * 4;
#pragma unroll
                for (int r = 0; r < 4; ++r) {
                    if (rbase + r < M) ssum += tanhf(acc[i][j][r] + bj) * qj;
                }
            }
        }
#pragma unroll
        for (int o = 32; o; o >>= 1) ssum += __shfl_xor(ssum, o);
        __syncthreads();  // all waves done with LDS before reuse for reduction
        float* red = (float*)&Ah[0][0];
        if (lane == 0) red[wv] = ssum;
        __syncthreads();
        if (tid == 0) {
            float s = 0.f;
#pragma unroll
            for (int k = 0; k < 8; ++k) s += red[k];
            atomicAdd(score, s);
        }
    }
}

// ---------------- per-node attention scores: s_i[n] = h[n,:] . v_i ----------------

template <int NV>
__global__ void scores_kernel(const float* __restrict__ h, int n, int D,
                              const float* __restrict__ v0, const float* __restrict__ v1,
                              const float* __restrict__ v2, const float* __restrict__ v3,
                              float* __restrict__ s0, float* __restrict__ s1,
                              float* __restrict__ s2, float* __restrict__ s3)
{
    const int lane = threadIdx.x & 63;
    int wid = (blockIdx.x * blockDim.x + threadIdx.x) >> 6;
    const int nw = (gridDim.x * blockDim.x) >> 6;
    for (int node = wid; node < n; node += nw) {
        const float* row = h + (size_t)node * D;
        float a0 = 0, a1 = 0, a2 = 0, a3 = 0;
        for (int d = lane * 4; d < D; d += 256) {
            float4 x = *(const float4*)&row[d];
            float4 w = *(const float4*)&v0[d];
            a0 += x.x * w.x + x.y * w.y + x.z * w.z + x.w * w.w;
            if (NV > 1) { float4 u = *(const float4*)&v1[d]; a1 += x.x * u.x + x.y * u.y + x.z * u.z + x.w * u.w; }
            if (NV > 2) { float4 u = *(const float4*)&v2[d]; a2 += x.x * u.x + x.y * u.y + x.z * u.z + x.w * u.w; }
            if (NV > 3) { float4 u = *(const float4*)&v3[d]; a3 += x.x * u.x + x.y * u.y + x.z * u.z + x.w * u.w; }
        }
#pragma unroll
        for (int o = 32; o; o >>= 1) {
            a0 += __shfl_xor(a0, o);
            if (NV > 1) a1 += __shfl_xor(a1, o);
            if (NV > 2) a2 += __shfl_xor(a2, o);
            if (NV > 3) a3 += __shfl_xor(a3, o);
        }
        if (lane == 0) {
            s0[node] = a0;
            if (NV > 1) s1[node] = a1;
            if (NV > 2) s2[node] = a2;
            if (NV > 3) s3[node] = a3;
        }
    }
}

// ---------------- edge scalar phases ----------------

__global__ void count_kernel(const void* __restrict__ e, int E, const int* __restrict__ flag,
                             int* __restrict__ cnt) {
    int i = blockIdx.x * blockDim.x + threadIdx.x;
    if (i >= E) return;
    int f = *flag;
    atomicAdd(&cnt[edge_at(e, (size_t)E + i, f)], 1);
}

// wave-shfl scan: 4 barriers per 1024-chunk (vs 20 for Hillis-Steele in LDS)
__global__ void scan_kernel(const int* __restrict__ cnt, int n, int* __restrict__ offs) {
    __shared__ int wsum[16];
    __shared__ int carry_s;
    const int t = threadIdx.x;           // 1024 threads = 16 waves
    const int lane = t & 63, w = t >> 6;
    if (t == 0) carry_s = 0;
    __syncthreads();
    for (int base = 0; base < n; base += 1024) {
        int v = (base + t < n) ? cnt[base + t] : 0;
        int x = v;
#pragma unroll
        for (int o = 1; o < 64; o <<= 1) {
            int y = __shfl_up(x, o);
            if (lane >= o) x += y;
        }
        if (lane == 63) wsum[w] = x;
        __syncthreads();
        if (w == 0 && lane < 16) {
            int s = wsum[lane];
#pragma unroll
            for (int o = 1; o < 16; o <<= 1) {
                int y = __shfl_up(s, o);
                if (lane >= o) s += y;
            }
            wsum[lane] = s;  // inclusive wave-sum scan
        }
        __syncthreads();
        const int carry = carry_s;
        const int woff = (w > 0) ? wsum[w - 1] : 0;
        if (base + t < n) offs[base + t] = carry + woff + x - v;  // exclusive
        __syncthreads();
        if (t == 1023) carry_s = carry + wsum[15];
        __syncthreads();
    }
    if (t == 0) offs[n] = carry_s;
}

__global__ void scatter_kernel(const void* __restrict__ e, int E, const int* __restrict__ flag,
                               int* __restrict__ cursor, int* __restrict__ eids) {
    int i = blockIdx.x * blockDim.x + threadIdx.x;
    if (i >= E) return;
    int f = *flag;
    int dst = edge_at(e, (size_t)E + i, f);
    int slot = atomicAdd(&cursor[dst], 1);
    eids[slot] = i;
}

__global__ void edge_alpha_max_kernel(const void* __restrict__ e, int E, const int* __restrict__ flag,
                                      const float* __restrict__ ssrc, const float* __restrict__ sdst,
                                      float* __restrict__ alpha, unsigned* __restrict__ mmono) {
    int i = blockIdx.x * blockDim.x + threadIdx.x;
    if (i >= E) return;
    int f = *flag;
    int s = edge_at(e, i, f);
    int d = edge_at(e, (size_t)E + i, f);
    float a = ssrc[s] + sdst[d];
    a = (a >= 0.f) ? a : 0.2f * a;  // leaky_relu 0.2
    alpha[i] = a;
    atomicMax(&mmono[d], f2mono(a));
}

__global__ void edge_exp_sum_kernel(const void* __restrict__ e, int E, const int* __restrict__ flag,
                                    const unsigned* __restrict__ mmono,
                                    float* __restrict__ alpha_ev, float* __restrict__ denom) {
    int i = blockIdx.x * blockDim.x + threadIdx.x;
    if (i >= E) return;
    int f = *flag;
    int d = edge_at(e, (size_t)E + i, f);
    float m = mono2f(mmono[d]);
    float ev = expf(alpha_ev[i] - m);
    alpha_ev[i] = ev;
    atomicAdd(&denom[d], ev);
}

// ---------------- CSR aggregation: out[dst,:] = relu( sum_e w_e * h_src[src_e,:] ) --
// 1-deep software pipeline: next edge's eid->src->ev chain overlaps current row gather.

template <int DW>  // floats per lane: D/64
__global__ __launch_bounds__(256) void agg_kernel(
    const int* __restrict__ offs, const int* __restrict__ eids,
    const void* __restrict__ e, const int* __restrict__ flag,
    const float* __restrict__ ev, const float* __restrict__ denom,
    const float* __restrict__ hsrc, float* __restrict__ out,
    int n_dst, int E, int D)
{
    const int lane = threadIdx.x & 63;
    int wid = (blockIdx.x * blockDim.x + threadIdx.x) >> 6;
    const int nw = (gridDim.x * blockDim.x) >> 6;
    const int f = *flag;
    for (int dst = wid; dst < n_dst; dst += nw) {
        int beg = offs[dst], end = offs[dst + 1];
        float acc[DW] = {};
        float rden = (end > beg) ? 1.f / denom[dst] : 0.f;
        int src_n = 0; float ev_n = 0.f;
        if (beg < end) {
            int e0 = eids[beg];
            src_n = edge_at(e, e0, f);
            ev_n = ev[e0];
        }
        for (int j = beg; j < end; ++j) {
            const int src = src_n;
            const float w = ev_n * rden;
            if (j + 1 < end) {
                int en = eids[j + 1];
                src_n = edge_at(e, en, f);
                ev_n = ev[en];
            }
            const float* row = hsrc + (size_t)src * D + lane * DW;
#pragma unroll
            for (int c = 0; c < DW; c += 4) {
                float4 v = *(const float4*)&row[c];
                acc[c + 0] += v.x * w; acc[c + 1] += v.y * w;
                acc[c + 2] += v.z * w; acc[c + 3] += v.w * w;
            }
        }
        float* orow = out + (size_t)dst * D + lane * DW;
#pragma unroll
        for (int c = 0; c < DW; c += 4) {
            float4 v = make_float4(fmaxf(acc[c + 0], 0.f), fmaxf(acc[c + 1], 0.f),
                                   fmaxf(acc[c + 2], 0.f), fmaxf(acc[c + 3], 0.f));
            *(float4*)&orow[c] = v;
        }
    }
}

// ---------------- semantic attention tail ----------------

__global__ void softmax2_kernel(const float* __restrict__ score, float invN, float* __restrict__ w) {
    if (threadIdx.x == 0 && blockIdx.x == 0) {
        float s0 = score[0] * invN, s1 = score[1] * invN;
        float m = fmaxf(s0, s1);
        float e0 = expf(s0 - m), e1 = expf(s1 - m);
        float r = 1.f / (e0 + e1);
        w[0] = e0 * r;
        w[1] = e1 * r;
    }
}

__global__ void combine2_kernel(const float4* __restrict__ a, const float4* __restrict__ b,
                                const float* __restrict__ w, float4* __restrict__ o, int n4) {
    float w0 = w[0], w1 = w[1];
    for (int i = blockIdx.x * blockDim.x + threadIdx.x; i < n4; i += gridDim.x * blockDim.x) {
        float4 x = a[i], y = b[i];
        o[i] = make_float4(w0 * x.x + w1 * y.x, w0 * x.y + w1 * y.y,
                           w0 * x.z + w1 * y.z, w0 * x.w + w1 * y.w);
    }
}

// ---------------- host orchestration ----------------

extern "C" void kernel_launch(void* const* d_in, const int* in_sizes, int n_in,
                              void* d_out, int out_size, void* d_ws, size_t ws_size,
                              hipStream_t stream) {
    const float* x_a  = (const float*)d_in[0];
    const float* x_p  = (const float*)d_in[1];
    const float* W1   = (const float*)d_in[2];
    const float* b1   = (const float*)d_in[3];
    const float* att1 = (const float*)d_in[4];
    const float* kW1  = (const float*)d_in[5];
    const float* kb1  = (const float*)d_in[6];
    const float* q1   = (const float*)d_in[7];
    const float* W2   = (const float*)d_in[8];
    const float* b2   = (const float*)d_in[9];
    const float* att2 = (const float*)d_in[10];
    const float* kW2  = (const float*)d_in[11];
    const float* kb2  = (const float*)d_in[12];
    const float* q2   = (const float*)d_in[13];
    const void* e_ap  = d_in[14];
    const void* e_pa  = d_in[15];
    const void* e_aa  = d_in[16];
    float* out = (float*)d_out;

    size_t off = 0;
    auto ALLOC = [&](size_t nbytes) -> void* {
        void* p = (char*)d_ws + off;
        off += (nbytes + 255) & ~(size_t)255;
        return p;
    };
    float* bufA = (float*)ALLOC((size_t)NPAP * DHID * 4);  // h_p -> out_p(x2_p)
    float* bufB = (float*)ALLOC((size_t)NA * DHID * 4);    // h_a -> h2_p
    float* bufC = (float*)ALLOC((size_t)NA * DHID * 4);    // out_a1 -> x2_a -> oa1_2|oa2_2
    float* bufD = (float*)ALLOC((size_t)NA * DHID * 4);    // out_a2 -> h2_a
    float* sa_w  = (float*)ALLOC((size_t)NA * 4);
    float* sa_pd = (float*)ALLOC((size_t)NA * 4);
    float* sa_as = (float*)ALLOC((size_t)NA * 4);
    float* sa_ad = (float*)ALLOC((size_t)NA * 4);
    float* sp_wd = (float*)ALLOC((size_t)NPAP * 4);
    float* sp_ps = (float*)ALLOC((size_t)NPAP * 4);
    float* alphab = (float*)ALLOC((size_t)EAP * 4);
    unsigned* mmono = (unsigned*)ALLOC((size_t)NPAP * 4);
    float* denom = (float*)ALLOC((size_t)NPAP * 4);
    int* cnt    = (int*)ALLOC((size_t)(NPAP + 1) * 4);
    int* cursor = (int*)ALLOC((size_t)(NPAP + 1) * 4);
    int* offs_ap = (int*)ALLOC((size_t)(NPAP + 1) * 4);
    int* offs_pa = (int*)ALLOC((size_t)(NA + 1) * 4);
    int* offs_aa = (int*)ALLOC((size_t)(NA + 1) * 4);
    int* eids_ap = (int*)ALLOC((size_t)EAP * 4);
    int* eids_pa = (int*)ALLOC((size_t)EPA * 4);
    int* eids_aa = (int*)ALLOC((size_t)EAA * 4);
    float* score = (float*)ALLOC(8 * 4);
    float* wsem  = (float*)ALLOC(2 * 4);
    int* eflag   = (int*)ALLOC(4);
    if (off > ws_size) return;  // insufficient scratch -> visible failure

    // bth/btl (512KB each) alias alphab (1.6MB): alphab is only live inside an
    // edge_attn phase; no GEMM runs between its producer and consumers (stream order).
    u16* bth = (u16*)alphab;
    u16* btl = bth + 512 * 512;

    hipStream_t s = stream;

    detect_kernel<<<1, 256, 0, s>>>((const unsigned*)e_ap, 1024, eflag);

    auto build_csr = [&](const void* ei, int E, int ndst, int* offs, int* eids) {
        int gn = (ndst + 255) / 256;
        int ge = (E + 255) / 256;
        fill_u32_kernel<<<gn, 256, 0, s>>>((unsigned*)cnt, 0u, ndst);
        count_kernel<<<ge, 256, 0, s>>>(ei, E, eflag, cnt);
        scan_kernel<<<1, 1024, 0, s>>>(cnt, ndst, offs);
        copy_i32_kernel<<<gn, 256, 0, s>>>(offs, cursor, ndst);
        scatter_kernel<<<ge, 256, 0, s>>>(ei, E, eflag, cursor, eids);
    };
    build_csr(e_ap, EAP, NPAP, offs_ap, eids_ap);
    build_csr(e_pa, EPA, NA, offs_pa, eids_pa);
    build_csr(e_aa, EAA, NA, offs_aa, eids_aa);

    auto gemm = [&](const float* A_, const float* B_, const float* bias_, float* C_,
                    int M, int N, int K, const float* qv, float* sc) {
        conv_bt_kernel<<<dim3(N / 32, K / 32), dim3(32, 8), 0, s>>>(B_, bth, btl, K, N);
        int gx = N / 128;
        int gy = (M + 255) / 256;
        int nwg = gx * gy;
        if (qv)
            mfma_gemm_kernel<true><<<nwg, 512, 0, s>>>(A_, bth, btl, bias_, nullptr, M, N, K, qv, sc, gx);
        else
            mfma_gemm_kernel<false><<<nwg, 512, 0, s>>>(A_, bth, btl, bias_, C_, M, N, K, nullptr, nullptr, gx);
    };

    auto edge_attn = [&](const void* ei, int E, int ndst, const float* ssrc, const float* sdst_,
                         const int* offs, const int* eids, const float* hsrc, float* outp, int D) {
        int gn = (ndst + 255) / 256;
        int ge = (E + 255) / 256;
        fill_u32_kernel<<<gn, 256, 0, s>>>(mmono, MONO_NEG_INF, ndst);
        fill_u32_kernel<<<gn, 256, 0, s>>>((unsigned*)denom, 0u, ndst);
        edge_alpha_max_kernel<<<ge, 256, 0, s>>>(ei, E, eflag, ssrc, sdst_, alphab, mmono);
        edge_exp_sum_kernel<<<ge, 256, 0, s>>>(ei, E, eflag, mmono, alphab, denom);
        int gw = (ndst + 3) / 4;
        if (D == 512)
            agg_kernel<8><<<gw, 256, 0, s>>>(offs, eids, ei, eflag, alphab, denom, hsrc, outp, ndst, E, D);
        else
            agg_kernel<4><<<gw, 256, 0, s>>>(offs, eids, ei, eflag, alphab, denom, hsrc, outp, ndst, E, D);
    };

    auto semantic = [&](const float* o1, const float* o2, const float* kW, const float* kb,
                        const float* q, int D, float* dst) {
        fill_u32_kernel<<<1, 64, 0, s>>>((unsigned*)score, 0u, 2);
        gemm(o1, kW, kb, nullptr, NA, D, D, q, &score[0]);
        gemm(o2, kW, kb, nullptr, NA, D, D, q, &score[1]);
        softmax2_kernel<<<1, 64, 0, s>>>(score, 1.f / (float)NA, wsem);
        combine2_kernel<<<2048, 256, 0, s>>>((const float4*)o1, (const float4*)o2, wsem,
                                             (float4*)dst, NA * D / 4);
    };

    // ---------------- layer 1 (D = 512) ----------------
    float* h_a = bufB;
    float* h_p = bufA;
    gemm(x_a, W1, b1, h_a, NA, DHID, DIN, nullptr, nullptr);
    gemm(x_p, W1 + (size_t)DIN * DHID, b1 + DHID, h_p, NPAP, DHID, DIN, nullptr, nullptr);

    {
        int ga = (NA + 3) / 4 < 4096 ? (NA + 3) / 4 : 4096;
        int gp = (NPAP + 3) / 4 < 4096 ? (NPAP + 3) / 4 : 4096;
        scores_kernel<4><<<ga, 256, 0, s>>>(h_a, NA, DHID,
            att1 + 0 * DHID, att1 + 3 * DHID, att1 + 4 * DHID, att1 + 5 * DHID,
            sa_w, sa_pd, sa_as, sa_ad);
        scores_kernel<2><<<gp, 256, 0, s>>>(h_p, NPAP, DHID,
            att1 + 1 * DHID, att1 + 2 * DHID, nullptr, nullptr,
            sp_wd, sp_ps, nullptr, nullptr);
    }

    edge_attn(e_pa, EPA, NA, sp_ps, sa_pd, offs_pa, eids_pa, h_p, bufC, DHID);  // out_a1
    edge_attn(e_aa, EAA, NA, sa_as, sa_ad, offs_aa, eids_aa, h_a, bufD, DHID);  // out_a2
    edge_attn(e_ap, EAP, NPAP, sa_w, sp_wd, offs_ap, eids_ap, h_a, bufA, DHID); // out_p

    semantic(bufC, bufD, kW1, kb1, q1, DHID, bufC);  // x2_a in bufC; x2_p = bufA

    // ---------------- layer 2 (D = 256) ----------------
    float* h2a = bufD;
    float* h2p = bufB;
    gemm(bufC, W2, b2, h2a, NA, DOUT, DHID, nullptr, nullptr);
    gemm(bufA, W2 + (size_t)DHID * DOUT, b2 + DOUT, h2p, NPAP, DOUT, DHID, nullptr, nullptr);

    {
        int ga = (NA + 3) / 4 < 4096 ? (NA + 3) / 4 : 4096;
        int gp = (NPAP + 3) / 4 < 4096 ? (NPAP + 3) / 4 : 4096;
        scores_kernel<3><<<ga, 256, 0, s>>>(h2a, NA, DOUT,
            att2 + 3 * DOUT, att2 + 4 * DOUT, att2 + 5 * DOUT, nullptr,
            sa_pd, sa_as, sa_ad, nullptr);
        scores_kernel<1><<<gp, 256, 0, s>>>(h2p, NPAP, DOUT,
            att2 + 2 * DOUT, nullptr, nullptr, nullptr,
            sp_ps, nullptr, nullptr, nullptr);
    }

    float* oa1 = bufC;
    float* oa2 = bufC + (size_t)NA * DOUT;
    edge_attn(e_pa, EPA, NA, sp_ps, sa_pd, offs_pa, eids_pa, h2p, oa1, DOUT);
    edge_attn(e_aa, EAA, NA, sa_as, sa_ad, offs_aa, eids_aa, h2a, oa2, DOUT);

    semantic(oa1, oa2, kW2, kb2, q2, DOUT, out);
}

// Round 6
// 1997.643 us; speedup vs baseline: 4.3660x; 4.3660x over previous
//
#include <hip/hip_runtime.h>
#include <hip/hip_bf16.h>

#define NA 50000
#define NPAP 100000
#define DIN 512
#define DHID 512
#define DOUT 256
#define EAP 400000
#define EPA 400000
#define EAA 200000

typedef unsigned short u16;
typedef __attribute__((ext_vector_type(8))) short bf16x8;
typedef __attribute__((ext_vector_type(4))) float f32x4;

// ---------------- utility kernels ----------------

__global__ void fill_u32_kernel(unsigned* __restrict__ p, unsigned v, int n) {
    int i = blockIdx.x * blockDim.x + threadIdx.x;
    if (i < n) p[i] = v;
}

__global__ void copy_i32_kernel(const int* __restrict__ a, int* __restrict__ b, int n) {
    int i = blockIdx.x * blockDim.x + threadIdx.x;
    if (i < n) b[i] = a[i];
}

// Detect whether edge arrays are int64 (high word of every pair-slot zero) or int32.
__global__ void detect_kernel(const unsigned* __restrict__ e, int npairs, int* __restrict__ flag) {
    __shared__ int anyn;
    if (threadIdx.x == 0) anyn = 0;
    __syncthreads();
    unsigned local = 0;
    for (int i = threadIdx.x; i < npairs; i += blockDim.x) local |= e[2 * i + 1];
    if (local) atomicOr(&anyn, 1);
    __syncthreads();
    if (threadIdx.x == 0) flag[0] = (anyn == 0) ? 1 : 0;
}

__device__ inline int edge_at(const void* e, size_t idx, int i64) {
    return i64 ? (int)((const long long*)e)[idx] : ((const int*)e)[idx];
}

__device__ inline unsigned f2mono(float f) {
    unsigned u = __float_as_uint(f);
    return (u & 0x80000000u) ? ~u : (u | 0x80000000u);
}
__device__ inline float mono2f(unsigned u) {
    unsigned b = (u & 0x80000000u) ? (u ^ 0x80000000u) : ~u;
    return __uint_as_float(b);
}
#define MONO_NEG_INF 0x007FFFFFu  // f2mono(-inf)

// ---------------- B transpose + bf16 hi/lo split, GEMM-tile swizzled layout -------
// B: [K,N] f32 row-major. Output planes bth/btl laid out as
// [nblk][kblk][row 0..127][chunk 0..3][8 u16], where physical chunk p of row r
// holds logical k-chunk (p ^ ((r>>1)&3)).  This matches the GEMM's LDS tile
// byte-for-byte, so staging is a plain linear copy (conflict-free) and the
// swizzled ds_read is conflict-free too.

__global__ void conv_bt_kernel(const float* __restrict__ B, u16* __restrict__ bth,
                               u16* __restrict__ btl, int K, int N) {
    __shared__ float tile[32][33];
    const int nb = blockIdx.x * 32, kb = blockIdx.y * 32;
    const int tx = threadIdx.x, ty = threadIdx.y;
    const int KBLK = K >> 5;
    for (int i = ty; i < 32; i += 8)
        tile[i][tx] = B[(size_t)(kb + i) * N + nb + tx];
    __syncthreads();
    for (int i = ty; i < 32; i += 8) {
        float v = tile[tx][i];  // = B[kb+tx][nb+i] -> n = nb+i, k = kb+tx
        unsigned u = __float_as_uint(v);
        unsigned h = (u + 0x7FFFu + ((u >> 16) & 1u)) >> 16;  // RNE for hi
        float hf = __uint_as_float(h << 16);
        float r = v - hf;                                      // exact residual
        unsigned l = __float_as_uint(r) >> 16;                 // trunc for lo
        const int n = nb + i, k = kb + tx;
        const int nblk = n >> 7, row = n & 127;
        const int kblk = k >> 5, kc = (k & 31) >> 3, ke = k & 7;
        const int cph = kc ^ ((row >> 1) & 3);
        size_t o = (((size_t)(nblk * KBLK + kblk) * 128 + row) << 5) + (cph << 3) + ke;
        bth[o] = (u16)h;
        btl[o] = (u16)l;
    }
}

// ---------------- split-bf16 MFMA GEMM: C[M,N] = A[M,K] @ B[K,N] + bias ----------
// R4-proven structure: 128x128 tile, 256 threads (4 waves), single-buffered
// 32 KB LDS, 2-barrier loop.  launch_bounds(256,4): 128 total regs/thread
// (64 VGPR + 64 acc, measured R4) x 4 waves = 512 = full SIMD budget ->
// 4 blocks/CU = 16 waves/CU.  A fp32 reg-staged + split at store; B copied
// linearly from pre-swizzled global tiles. 1-D grid + bijective XCD swizzle.
// SCORE mode: atomicAdd(score, sum(tanh(C+bias)*q[col])).

template <bool SCORE>
__global__ __launch_bounds__(256, 4) void mfma_gemm_kernel(
    const float* __restrict__ A, const u16* __restrict__ Bth,
    const u16* __restrict__ Btl, const float* __restrict__ bias,
    float* __restrict__ C, int M, int N, int K,
    const float* __restrict__ qv, float* __restrict__ score, int gx)
{
    __shared__ u16 Ah[128][32];
    __shared__ u16 Al[128][32];
    __shared__ u16 Bh[128][32];
    __shared__ u16 Bl[128][32];

    // bijective XCD chunk remap (m204): XCD k processes a contiguous wg range.
    const int nwg = gridDim.x;
    const int bid = blockIdx.x;
    const int qc = nwg >> 3, rc = nwg & 7;
    const int xcd = bid & 7, idx = bid >> 3;
    const int wg = (xcd < rc ? xcd * (qc + 1) : rc * (qc + 1) + (xcd - rc) * qc) + idx;
    const int bx = wg % gx, by = wg / gx;
    const int m0 = by * 128;
    const int n0 = bx * 128;

    const int tid = threadIdx.x;
    const int lane = tid & 63;
    const int wv = tid >> 6;           // wave 0..3
    const int wm = wv >> 1, wn = wv & 1;
    const int fr = lane & 15;          // row/col within 16x16 fragment
    const int kg = lane >> 4;          // k-group 0..3

    // A staging: thread handles 16 consecutive K elems of one row
    const int srow = tid >> 1;
    const int oh   = tid & 1;
    const bool a_ok = (m0 + srow) < M;
    const float* Ap = A + (size_t)(m0 + srow) * K + oh * 16;

    // swizzled LDS write positions for A (u16 units)
    const int swc = (srow >> 1) & 3;
    const int p0 = srow * 32 + ((((oh << 1) + 0) ^ swc) << 3);
    const int p1 = srow * 32 + ((((oh << 1) + 1) ^ swc) << 3);
    // swizzled read chunk (row bits 1..2 come from fr for all fragment rows)
    const int rdc = (kg ^ ((fr >> 1) & 3)) << 3;

    // B staging: per plane, wave wv copies slots {wv, wv+4}; slot s = 512 u16.
    const int KBLK = K >> 5;
    const size_t btile0 = ((size_t)(n0 >> 7) * KBLK) << 12;  // *4096 u16 per tile
    const int bso0 = wv * 512 + lane * 8;
    const int bso1 = (wv + 4) * 512 + lane * 8;

    f32x4 acc[4][4] = {};

    const int nt = K >> 5;
    for (int t = 0; t < nt; ++t) {
        __syncthreads();  // barrier 1: previous compute done reading LDS

        // ---- stage phase ----
        {
            const int k0 = t << 5;
            float ar[16];
            if (a_ok) {
                float4 v;
                v = *(const float4*)(Ap + k0);      ar[0]=v.x;  ar[1]=v.y;  ar[2]=v.z;  ar[3]=v.w;
                v = *(const float4*)(Ap + k0 + 4);  ar[4]=v.x;  ar[5]=v.y;  ar[6]=v.z;  ar[7]=v.w;
                v = *(const float4*)(Ap + k0 + 8);  ar[8]=v.x;  ar[9]=v.y;  ar[10]=v.z; ar[11]=v.w;
                v = *(const float4*)(Ap + k0 + 12); ar[12]=v.x; ar[13]=v.y; ar[14]=v.z; ar[15]=v.w;
            } else {
#pragma unroll
                for (int c = 0; c < 16; ++c) ar[c] = 0.f;
            }
            const u16* bt = Bth + btile0 + ((size_t)t << 12);
            const u16* blt = Btl + btile0 + ((size_t)t << 12);
            uint4 bh0 = *(const uint4*)(bt + bso0);
            uint4 bh1 = *(const uint4*)(bt + bso1);
            uint4 bl0 = *(const uint4*)(blt + bso0);
            uint4 bl1 = *(const uint4*)(blt + bso1);

            unsigned hw[8], lw[8];
#pragma unroll
            for (int c = 0; c < 8; ++c) {
                // truncation split: a = hi + lo + eps, |eps| <= 2^-16 |a|
                unsigned u0 = __float_as_uint(ar[2 * c]);
                unsigned h0 = u0 >> 16;
                float r0 = ar[2 * c] - __uint_as_float(h0 << 16);
                unsigned l0 = __float_as_uint(r0) >> 16;
                unsigned u1 = __float_as_uint(ar[2 * c + 1]);
                unsigned h1 = u1 >> 16;
                float r1 = ar[2 * c + 1] - __uint_as_float(h1 << 16);
                unsigned l1 = __float_as_uint(r1) >> 16;
                hw[c] = h0 | (h1 << 16);
                lw[c] = l0 | (l1 << 16);
            }
            u16* ahp = &Ah[0][0];
            u16* alp = &Al[0][0];
            *(uint4*)&ahp[p0] = make_uint4(hw[0], hw[1], hw[2], hw[3]);
            *(uint4*)&ahp[p1] = make_uint4(hw[4], hw[5], hw[6], hw[7]);
            *(uint4*)&alp[p0] = make_uint4(lw[0], lw[1], lw[2], lw[3]);
            *(uint4*)&alp[p1] = make_uint4(lw[4], lw[5], lw[6], lw[7]);
            u16* bhp = &Bh[0][0];
            u16* blp = &Bl[0][0];
            *(uint4*)&bhp[bso0] = bh0;
            *(uint4*)&bhp[bso1] = bh1;
            *(uint4*)&blp[bso0] = bl0;
            *(uint4*)&blp[bso1] = bl1;
        }

        __syncthreads();  // barrier 2: stores visible

        // ---- compute phase ----
        bf16x8 afh[4], afl[4], bfh[4], bfl[4];
#pragma unroll
        for (int i = 0; i < 4; ++i) {
            const int aoff = (wm * 64 + i * 16 + fr) * 32 + rdc;
            const int boff = (wn * 64 + i * 16 + fr) * 32 + rdc;
            afh[i] = *(const bf16x8*)&Ah[0][aoff];
            afl[i] = *(const bf16x8*)&Al[0][aoff];
            bfh[i] = *(const bf16x8*)&Bh[0][boff];
            bfl[i] = *(const bf16x8*)&Bl[0][boff];
        }
#pragma unroll
        for (int i = 0; i < 4; ++i)
#pragma unroll
            for (int j = 0; j < 4; ++j) {
                acc[i][j] = __builtin_amdgcn_mfma_f32_16x16x32_bf16(afh[i], bfh[j], acc[i][j], 0, 0, 0);
                acc[i][j] = __builtin_amdgcn_mfma_f32_16x16x32_bf16(afl[i], bfh[j], acc[i][j], 0, 0, 0);
                acc[i][j] = __builtin_amdgcn_mfma_f32_16x16x32_bf16(afh[i], bfl[j], acc[i][j], 0, 0, 0);
            }
    }

    // C/D layout (m89/m91-verified): col = lane&15, row = (lane>>4)*4 + reg
    if (!SCORE) {
#pragma unroll
        for (int j = 0; j < 4; ++j) {
            const int col = n0 + wn * 64 + j * 16 + fr;
            const float bj = bias[col];
#pragma unroll
            for (int i = 0; i < 4; ++i) {
                const int rbase = m0 + wm * 64 + i * 16 + kg * 4;
#pragma unroll
                for (int r = 0; r < 4; ++r) {
                    const int grow = rbase + r;
                    if (grow < M) C[(size_t)grow * N + col] = acc[i][j][r] + bj;
                }
            }
        }
    } else {
        float ssum = 0.f;
#pragma unroll
        for (int j = 0; j < 4; ++j) {
            const int col = n0 + wn * 64 + j * 16 + fr;
            const float bj = bias[col];
            const float qj = qv[col];
#pragma unroll
            for (int i = 0; i < 4; ++i) {
                const int rbase = m0 + wm * 64 + i * 16 + kg * 4;
#pragma unroll
                for (int r = 0; r < 4; ++r) {
                    if (rbase + r < M) ssum += tanhf(acc[i][j][r] + bj) * qj;
                }
            }
        }
#pragma unroll
        for (int o = 32; o; o >>= 1) ssum += __shfl_xor(ssum, o);
        __syncthreads();  // all waves done with LDS before reuse for reduction
        float* red = (float*)&Ah[0][0];
        if (lane == 0) red[wv] = ssum;
        __syncthreads();
        if (tid == 0) atomicAdd(score, red[0] + red[1] + red[2] + red[3]);
    }
}

// ---------------- per-node attention scores: s_i[n] = h[n,:] . v_i ----------------

template <int NV>
__global__ void scores_kernel(const float* __restrict__ h, int n, int D,
                              const float* __restrict__ v0, const float* __restrict__ v1,
                              const float* __restrict__ v2, const float* __restrict__ v3,
                              float* __restrict__ s0, float* __restrict__ s1,
                              float* __restrict__ s2, float* __restrict__ s3)
{
    const int lane = threadIdx.x & 63;
    int wid = (blockIdx.x * blockDim.x + threadIdx.x) >> 6;
    const int nw = (gridDim.x * blockDim.x) >> 6;
    for (int node = wid; node < n; node += nw) {
        const float* row = h + (size_t)node * D;
        float a0 = 0, a1 = 0, a2 = 0, a3 = 0;
        for (int d = lane * 4; d < D; d += 256) {
            float4 x = *(const float4*)&row[d];
            float4 w = *(const float4*)&v0[d];
            a0 += x.x * w.x + x.y * w.y + x.z * w.z + x.w * w.w;
            if (NV > 1) { float4 u = *(const float4*)&v1[d]; a1 += x.x * u.x + x.y * u.y + x.z * u.z + x.w * u.w; }
            if (NV > 2) { float4 u = *(const float4*)&v2[d]; a2 += x.x * u.x + x.y * u.y + x.z * u.z + x.w * u.w; }
            if (NV > 3) { float4 u = *(const float4*)&v3[d]; a3 += x.x * u.x + x.y * u.y + x.z * u.z + x.w * u.w; }
        }
#pragma unroll
        for (int o = 32; o; o >>= 1) {
            a0 += __shfl_xor(a0, o);
            if (NV > 1) a1 += __shfl_xor(a1, o);
            if (NV > 2) a2 += __shfl_xor(a2, o);
            if (NV > 3) a3 += __shfl_xor(a3, o);
        }
        if (lane == 0) {
            s0[node] = a0;
            if (NV > 1) s1[node] = a1;
            if (NV > 2) s2[node] = a2;
            if (NV > 3) s3[node] = a3;
        }
    }
}

// ---------------- edge scalar phases ----------------

__global__ void count_kernel(const void* __restrict__ e, int E, const int* __restrict__ flag,
                             int* __restrict__ cnt) {
    int i = blockIdx.x * blockDim.x + threadIdx.x;
    if (i >= E) return;
    int f = *flag;
    atomicAdd(&cnt[edge_at(e, (size_t)E + i, f)], 1);
}

// wave-shfl scan: 4 barriers per 1024-chunk (vs 20 for Hillis-Steele in LDS)
__global__ void scan_kernel(const int* __restrict__ cnt, int n, int* __restrict__ offs) {
    __shared__ int wsum[16];
    __shared__ int carry_s;
    const int t = threadIdx.x;           // 1024 threads = 16 waves
    const int lane = t & 63, w = t >> 6;
    if (t == 0) carry_s = 0;
    __syncthreads();
    for (int base = 0; base < n; base += 1024) {
        int v = (base + t < n) ? cnt[base + t] : 0;
        int x = v;
#pragma unroll
        for (int o = 1; o < 64; o <<= 1) {
            int y = __shfl_up(x, o);
            if (lane >= o) x += y;
        }
        if (lane == 63) wsum[w] = x;
        __syncthreads();
        if (w == 0 && lane < 16) {
            int s = wsum[lane];
#pragma unroll
            for (int o = 1; o < 16; o <<= 1) {
                int y = __shfl_up(s, o);
                if (lane >= o) s += y;
            }
            wsum[lane] = s;  // inclusive wave-sum scan
        }
        __syncthreads();
        const int carry = carry_s;
        const int woff = (w > 0) ? wsum[w - 1] : 0;
        if (base + t < n) offs[base + t] = carry + woff + x - v;  // exclusive
        __syncthreads();
        if (t == 1023) carry_s = carry + wsum[15];
        __syncthreads();
    }
    if (t == 0) offs[n] = carry_s;
}

__global__ void scatter_kernel(const void* __restrict__ e, int E, const int* __restrict__ flag,
                               int* __restrict__ cursor, int* __restrict__ eids) {
    int i = blockIdx.x * blockDim.x + threadIdx.x;
    if (i >= E) return;
    int f = *flag;
    int dst = edge_at(e, (size_t)E + i, f);
    int slot = atomicAdd(&cursor[dst], 1);
    eids[slot] = i;
}

__global__ void edge_alpha_max_kernel(const void* __restrict__ e, int E, const int* __restrict__ flag,
                                      const float* __restrict__ ssrc, const float* __restrict__ sdst,
                                      float* __restrict__ alpha, unsigned* __restrict__ mmono) {
    int i = blockIdx.x * blockDim.x + threadIdx.x;
    if (i >= E) return;
    int f = *flag;
    int s = edge_at(e, i, f);
    int d = edge_at(e, (size_t)E + i, f);
    float a = ssrc[s] + sdst[d];
    a = (a >= 0.f) ? a : 0.2f * a;  // leaky_relu 0.2
    alpha[i] = a;
    atomicMax(&mmono[d], f2mono(a));
}

__global__ void edge_exp_sum_kernel(const void* __restrict__ e, int E, const int* __restrict__ flag,
                                    const unsigned* __restrict__ mmono,
                                    float* __restrict__ alpha_ev, float* __restrict__ denom) {
    int i = blockIdx.x * blockDim.x + threadIdx.x;
    if (i >= E) return;
    int f = *flag;
    int d = edge_at(e, (size_t)E + i, f);
    float m = mono2f(mmono[d]);
    float ev = expf(alpha_ev[i] - m);
    alpha_ev[i] = ev;
    atomicAdd(&denom[d], ev);
}

// ---------------- CSR aggregation: out[dst,:] = relu( sum_e w_e * h_src[src_e,:] ) --
// 1-deep software pipeline: next edge's eid->src->ev chain overlaps current row gather.

template <int DW>  // floats per lane: D/64
__global__ __launch_bounds__(256) void agg_kernel(
    const int* __restrict__ offs, const int* __restrict__ eids,
    const void* __restrict__ e, const int* __restrict__ flag,
    const float* __restrict__ ev, const float* __restrict__ denom,
    const float* __restrict__ hsrc, float* __restrict__ out,
    int n_dst, int E, int D)
{
    const int lane = threadIdx.x & 63;
    int wid = (blockIdx.x * blockDim.x + threadIdx.x) >> 6;
    const int nw = (gridDim.x * blockDim.x) >> 6;
    const int f = *flag;
    for (int dst = wid; dst < n_dst; dst += nw) {
        int beg = offs[dst], end = offs[dst + 1];
        float acc[DW] = {};
        float rden = (end > beg) ? 1.f / denom[dst] : 0.f;
        int src_n = 0; float ev_n = 0.f;
        if (beg < end) {
            int e0 = eids[beg];
            src_n = edge_at(e, e0, f);
            ev_n = ev[e0];
        }
        for (int j = beg; j < end; ++j) {
            const int src = src_n;
            const float w = ev_n * rden;
            if (j + 1 < end) {
                int en = eids[j + 1];
                src_n = edge_at(e, en, f);
                ev_n = ev[en];
            }
            const float* row = hsrc + (size_t)src * D + lane * DW;
#pragma unroll
            for (int c = 0; c < DW; c += 4) {
                float4 v = *(const float4*)&row[c];
                acc[c + 0] += v.x * w; acc[c + 1] += v.y * w;
                acc[c + 2] += v.z * w; acc[c + 3] += v.w * w;
            }
        }
        float* orow = out + (size_t)dst * D + lane * DW;
#pragma unroll
        for (int c = 0; c < DW; c += 4) {
            float4 v = make_float4(fmaxf(acc[c + 0], 0.f), fmaxf(acc[c + 1], 0.f),
                                   fmaxf(acc[c + 2], 0.f), fmaxf(acc[c + 3], 0.f));
            *(float4*)&orow[c] = v;
        }
    }
}

// ---------------- semantic attention tail ----------------

__global__ void softmax2_kernel(const float* __restrict__ score, float invN, float* __restrict__ w) {
    if (threadIdx.x == 0 && blockIdx.x == 0) {
        float s0 = score[0] * invN, s1 = score[1] * invN;
        float m = fmaxf(s0, s1);
        float e0 = expf(s0 - m), e1 = expf(s1 - m);
        float r = 1.f / (e0 + e1);
        w[0] = e0 * r;
        w[1] = e1 * r;
    }
}

__global__ void combine2_kernel(const float4* __restrict__ a, const float4* __restrict__ b,
                                const float* __restrict__ w, float4* __restrict__ o, int n4) {
    float w0 = w[0], w1 = w[1];
    for (int i = blockIdx.x * blockDim.x + threadIdx.x; i < n4; i += gridDim.x * blockDim.x) {
        float4 x = a[i], y = b[i];
        o[i] = make_float4(w0 * x.x + w1 * y.x, w0 * x.y + w1 * y.y,
                           w0 * x.z + w1 * y.z, w0 * x.w + w1 * y.w);
    }
}

// ---------------- host orchestration ----------------

extern "C" void kernel_launch(void* const* d_in, const int* in_sizes, int n_in,
                              void* d_out, int out_size, void* d_ws, size_t ws_size,
                              hipStream_t stream) {
    const float* x_a  = (const float*)d_in[0];
    const float* x_p  = (const float*)d_in[1];
    const float* W1   = (const float*)d_in[2];
    const float* b1   = (const float*)d_in[3];
    const float* att1 = (const float*)d_in[4];
    const float* kW1  = (const float*)d_in[5];
    const float* kb1  = (const float*)d_in[6];
    const float* q1   = (const float*)d_in[7];
    const float* W2   = (const float*)d_in[8];
    const float* b2   = (const float*)d_in[9];
    const float* att2 = (const float*)d_in[10];
    const float* kW2  = (const float*)d_in[11];
    const float* kb2  = (const float*)d_in[12];
    const float* q2   = (const float*)d_in[13];
    const void* e_ap  = d_in[14];
    const void* e_pa  = d_in[15];
    const void* e_aa  = d_in[16];
    float* out = (float*)d_out;

    size_t off = 0;
    auto ALLOC = [&](size_t nbytes) -> void* {
        void* p = (char*)d_ws + off;
        off += (nbytes + 255) & ~(size_t)255;
        return p;
    };
    float* bufA = (float*)ALLOC((size_t)NPAP * DHID * 4);  // h_p -> out_p(x2_p)
    float* bufB = (float*)ALLOC((size_t)NA * DHID * 4);    // h_a -> h2_p
    float* bufC = (float*)ALLOC((size_t)NA * DHID * 4);    // out_a1 -> x2_a -> oa1_2|oa2_2
    float* bufD = (float*)ALLOC((size_t)NA * DHID * 4);    // out_a2 -> h2_a
    float* sa_w  = (float*)ALLOC((size_t)NA * 4);
    float* sa_pd = (float*)ALLOC((size_t)NA * 4);
    float* sa_as = (float*)ALLOC((size_t)NA * 4);
    float* sa_ad = (float*)ALLOC((size_t)NA * 4);
    float* sp_wd = (float*)ALLOC((size_t)NPAP * 4);
    float* sp_ps = (float*)ALLOC((size_t)NPAP * 4);
    float* alphab = (float*)ALLOC((size_t)EAP * 4);
    unsigned* mmono = (unsigned*)ALLOC((size_t)NPAP * 4);
    float* denom = (float*)ALLOC((size_t)NPAP * 4);
    int* cnt    = (int*)ALLOC((size_t)(NPAP + 1) * 4);
    int* cursor = (int*)ALLOC((size_t)(NPAP + 1) * 4);
    int* offs_ap = (int*)ALLOC((size_t)(NPAP + 1) * 4);
    int* offs_pa = (int*)ALLOC((size_t)(NA + 1) * 4);
    int* offs_aa = (int*)ALLOC((size_t)(NA + 1) * 4);
    int* eids_ap = (int*)ALLOC((size_t)EAP * 4);
    int* eids_pa = (int*)ALLOC((size_t)EPA * 4);
    int* eids_aa = (int*)ALLOC((size_t)EAA * 4);
    float* score = (float*)ALLOC(8 * 4);
    float* wsem  = (float*)ALLOC(2 * 4);
    int* eflag   = (int*)ALLOC(4);
    if (off > ws_size) return;  // insufficient scratch -> visible failure

    // bth/btl (512KB each) alias alphab (1.6MB): alphab is only live inside an
    // edge_attn phase; no GEMM runs between its producer and consumers (stream order).
    u16* bth = (u16*)alphab;
    u16* btl = bth + 512 * 512;

    hipStream_t s = stream;

    detect_kernel<<<1, 256, 0, s>>>((const unsigned*)e_ap, 1024, eflag);

    auto build_csr = [&](const void* ei, int E, int ndst, int* offs, int* eids) {
        int gn = (ndst + 255) / 256;
        int ge = (E + 255) / 256;
        fill_u32_kernel<<<gn, 256, 0, s>>>((unsigned*)cnt, 0u, ndst);
        count_kernel<<<ge, 256, 0, s>>>(ei, E, eflag, cnt);
        scan_kernel<<<1, 1024, 0, s>>>(cnt, ndst, offs);
        copy_i32_kernel<<<gn, 256, 0, s>>>(offs, cursor, ndst);
        scatter_kernel<<<ge, 256, 0, s>>>(ei, E, eflag, cursor, eids);
    };
    build_csr(e_ap, EAP, NPAP, offs_ap, eids_ap);
    build_csr(e_pa, EPA, NA, offs_pa, eids_pa);
    build_csr(e_aa, EAA, NA, offs_aa, eids_aa);

    auto gemm = [&](const float* A_, const float* B_, const float* bias_, float* C_,
                    int M, int N, int K, const float* qv, float* sc) {
        conv_bt_kernel<<<dim3(N / 32, K / 32), dim3(32, 8), 0, s>>>(B_, bth, btl, K, N);
        int gx = N / 128;
        int gy = (M + 127) / 128;
        int nwg = gx * gy;
        if (qv)
            mfma_gemm_kernel<true><<<nwg, 256, 0, s>>>(A_, bth, btl, bias_, nullptr, M, N, K, qv, sc, gx);
        else
            mfma_gemm_kernel<false><<<nwg, 256, 0, s>>>(A_, bth, btl, bias_, C_, M, N, K, nullptr, nullptr, gx);
    };

    auto edge_attn = [&](const void* ei, int E, int ndst, const float* ssrc, const float* sdst_,
                         const int* offs, const int* eids, const float* hsrc, float* outp, int D) {
        int gn = (ndst + 255) / 256;
        int ge = (E + 255) / 256;
        fill_u32_kernel<<<gn, 256, 0, s>>>(mmono, MONO_NEG_INF, ndst);
        fill_u32_kernel<<<gn, 256, 0, s>>>((unsigned*)denom, 0u, ndst);
        edge_alpha_max_kernel<<<ge, 256, 0, s>>>(ei, E, eflag, ssrc, sdst_, alphab, mmono);
        edge_exp_sum_kernel<<<ge, 256, 0, s>>>(ei, E, eflag, mmono, alphab, denom);
        int gw = (ndst + 3) / 4;
        if (D == 512)
            agg_kernel<8><<<gw, 256, 0, s>>>(offs, eids, ei, eflag, alphab, denom, hsrc, outp, ndst, E, D);
        else
            agg_kernel<4><<<gw, 256, 0, s>>>(offs, eids, ei, eflag, alphab, denom, hsrc, outp, ndst, E, D);
    };

    auto semantic = [&](const float* o1, const float* o2, const float* kW, const float* kb,
                        const float* q, int D, float* dst) {
        fill_u32_kernel<<<1, 64, 0, s>>>((unsigned*)score, 0u, 2);
        gemm(o1, kW, kb, nullptr, NA, D, D, q, &score[0]);
        gemm(o2, kW, kb, nullptr, NA, D, D, q, &score[1]);
        softmax2_kernel<<<1, 64, 0, s>>>(score, 1.f / (float)NA, wsem);
        combine2_kernel<<<2048, 256, 0, s>>>((const float4*)o1, (const float4*)o2, wsem,
                                             (float4*)dst, NA * D / 4);
    };

    // ---------------- layer 1 (D = 512) ----------------
    float* h_a = bufB;
    float* h_p = bufA;
    gemm(x_a, W1, b1, h_a, NA, DHID, DIN, nullptr, nullptr);
    gemm(x_p, W1 + (size_t)DIN * DHID, b1 + DHID, h_p, NPAP, DHID, DIN, nullptr, nullptr);

    {
        int ga = (NA + 3) / 4 < 4096 ? (NA + 3) / 4 : 4096;
        int gp = (NPAP + 3) / 4 < 4096 ? (NPAP + 3) / 4 : 4096;
        scores_kernel<4><<<ga, 256, 0, s>>>(h_a, NA, DHID,
            att1 + 0 * DHID, att1 + 3 * DHID, att1 + 4 * DHID, att1 + 5 * DHID,
            sa_w, sa_pd, sa_as, sa_ad);
        scores_kernel<2><<<gp, 256, 0, s>>>(h_p, NPAP, DHID,
            att1 + 1 * DHID, att1 + 2 * DHID, nullptr, nullptr,
            sp_wd, sp_ps, nullptr, nullptr);
    }

    edge_attn(e_pa, EPA, NA, sp_ps, sa_pd, offs_pa, eids_pa, h_p, bufC, DHID);  // out_a1
    edge_attn(e_aa, EAA, NA, sa_as, sa_ad, offs_aa, eids_aa, h_a, bufD, DHID);  // out_a2
    edge_attn(e_ap, EAP, NPAP, sa_w, sp_wd, offs_ap, eids_ap, h_a, bufA, DHID); // out_p

    semantic(bufC, bufD, kW1, kb1, q1, DHID, bufC);  // x2_a in bufC; x2_p = bufA

    // ---------------- layer 2 (D = 256) ----------------
    float* h2a = bufD;
    float* h2p = bufB;
    gemm(bufC, W2, b2, h2a, NA, DOUT, DHID, nullptr, nullptr);
    gemm(bufA, W2 + (size_t)DHID * DOUT, b2 + DOUT, h2p, NPAP, DOUT, DHID, nullptr, nullptr);

    {
        int ga = (NA + 3) / 4 < 4096 ? (NA + 3) / 4 : 4096;
        int gp = (NPAP + 3) / 4 < 4096 ? (NPAP + 3) / 4 : 4096;
        scores_kernel<3><<<ga, 256, 0, s>>>(h2a, NA, DOUT,
            att2 + 3 * DOUT, att2 + 4 * DOUT, att2 + 5 * DOUT, nullptr,
            sa_pd, sa_as, sa_ad, nullptr);
        scores_kernel<1><<<gp, 256, 0, s>>>(h2p, NPAP, DOUT,
            att2 + 2 * DOUT, nullptr, nullptr, nullptr,
            sp_ps, nullptr, nullptr, nullptr);
    }

    float* oa1 = bufC;
    float* oa2 = bufC + (size_t)NA * DOUT;
    edge_attn(e_pa, EPA, NA, sp_ps, sa_pd, offs_pa, eids_pa, h2p, oa1, DOUT);
    edge_attn(e_aa, EAA, NA, sa_as, sa_ad, offs_aa, eids_aa, h2a, oa2, DOUT);

    semantic(oa1, oa2, kW2, kb2, q2, DOUT, out);
}

// Round 7
// 1979.612 us; speedup vs baseline: 4.4058x; 1.0091x over previous
//
#include <hip/hip_runtime.h>
#include <hip/hip_bf16.h>

#define NA 50000
#define NPAP 100000
#define DIN 512
#define DHID 512
#define DOUT 256
#define EAP 400000
#define EPA 400000
#define EAA 200000

typedef unsigned short u16;
typedef __attribute__((ext_vector_type(8))) short bf16x8;
typedef __attribute__((ext_vector_type(4))) float f32x4;

// ---------------- utility kernels ----------------

__global__ void fill_u32_kernel(unsigned* __restrict__ p, unsigned v, int n) {
    int i = blockIdx.x * blockDim.x + threadIdx.x;
    if (i < n) p[i] = v;
}

// one launch: a[i]=va, b[i]=vb
__global__ void fill2_kernel(unsigned* __restrict__ a, unsigned va,
                             unsigned* __restrict__ b, unsigned vb, int n) {
    int i = blockIdx.x * blockDim.x + threadIdx.x;
    if (i < n) { a[i] = va; b[i] = vb; }
}

// Detect whether edge arrays are int64 (high word of every pair-slot zero) or int32.
__global__ void detect_kernel(const unsigned* __restrict__ e, int npairs, int* __restrict__ flag) {
    __shared__ int anyn;
    if (threadIdx.x == 0) anyn = 0;
    __syncthreads();
    unsigned local = 0;
    for (int i = threadIdx.x; i < npairs; i += blockDim.x) local |= e[2 * i + 1];
    if (local) atomicOr(&anyn, 1);
    __syncthreads();
    if (threadIdx.x == 0) flag[0] = (anyn == 0) ? 1 : 0;
}

__device__ inline int edge_at(const void* e, size_t idx, int i64) {
    return i64 ? (int)((const long long*)e)[idx] : ((const int*)e)[idx];
}

__device__ inline unsigned f2mono(float f) {
    unsigned u = __float_as_uint(f);
    return (u & 0x80000000u) ? ~u : (u | 0x80000000u);
}
__device__ inline float mono2f(unsigned u) {
    unsigned b = (u & 0x80000000u) ? (u ^ 0x80000000u) : ~u;
    return __uint_as_float(b);
}
#define MONO_NEG_INF 0x007FFFFFu  // f2mono(-inf)

// ---------------- B transpose + bf16 hi/lo split, GEMM-tile swizzled layout -------
// B: [K,N] f32 row-major. Output planes bth/btl laid out as
// [nblk][kblk][row 0..127][chunk 0..3][8 u16], where physical chunk p of row r
// holds logical k-chunk (p ^ ((r>>1)&3)).  This matches the GEMM's LDS tile
// byte-for-byte, so staging is a plain linear copy (conflict-free) and the
// swizzled ds_read is conflict-free too.

__global__ void conv_bt_kernel(const float* __restrict__ B, u16* __restrict__ bth,
                               u16* __restrict__ btl, int K, int N) {
    __shared__ float tile[32][33];
    const int nb = blockIdx.x * 32, kb = blockIdx.y * 32;
    const int tx = threadIdx.x, ty = threadIdx.y;
    const int KBLK = K >> 5;
    for (int i = ty; i < 32; i += 8)
        tile[i][tx] = B[(size_t)(kb + i) * N + nb + tx];
    __syncthreads();
    for (int i = ty; i < 32; i += 8) {
        float v = tile[tx][i];  // = B[kb+tx][nb+i] -> n = nb+i, k = kb+tx
        unsigned u = __float_as_uint(v);
        unsigned h = (u + 0x7FFFu + ((u >> 16) & 1u)) >> 16;  // RNE for hi
        float hf = __uint_as_float(h << 16);
        float r = v - hf;                                      // exact residual
        unsigned l = __float_as_uint(r) >> 16;                 // trunc for lo
        const int n = nb + i, k = kb + tx;
        const int nblk = n >> 7, row = n & 127;
        const int kblk = k >> 5, kc = (k & 31) >> 3, ke = k & 7;
        const int cph = kc ^ ((row >> 1) & 3);
        size_t o = (((size_t)(nblk * KBLK + kblk) * 128 + row) << 5) + (cph << 3) + ke;
        bth[o] = (u16)h;
        btl[o] = (u16)l;
    }
}

// ---------------- split-bf16 MFMA GEMM: C[M,N] = A[M,K] @ B[K,N] + bias ----------
// R4-proven structure: 128x128 tile, 256 threads (4 waves), single-buffered
// 32 KB LDS, 2-barrier loop, 4 blocks/CU requested. A fp32 reg-staged + split
// at store; B copied linearly from pre-swizzled global tiles. 1-D grid +
// bijective XCD swizzle. SCORE mode: atomicAdd(score, sum(tanh(C+bias)*q[col])).

template <bool SCORE>
__global__ __launch_bounds__(256, 4) void mfma_gemm_kernel(
    const float* __restrict__ A, const u16* __restrict__ Bth,
    const u16* __restrict__ Btl, const float* __restrict__ bias,
    float* __restrict__ C, int M, int N, int K,
    const float* __restrict__ qv, float* __restrict__ score, int gx)
{
    __shared__ u16 Ah[128][32];
    __shared__ u16 Al[128][32];
    __shared__ u16 Bh[128][32];
    __shared__ u16 Bl[128][32];

    // bijective XCD chunk remap (m204): XCD k processes a contiguous wg range.
    const int nwg = gridDim.x;
    const int bid = blockIdx.x;
    const int qc = nwg >> 3, rc = nwg & 7;
    const int xcd = bid & 7, idx = bid >> 3;
    const int wg = (xcd < rc ? xcd * (qc + 1) : rc * (qc + 1) + (xcd - rc) * qc) + idx;
    const int bx = wg % gx, by = wg / gx;
    const int m0 = by * 128;
    const int n0 = bx * 128;

    const int tid = threadIdx.x;
    const int lane = tid & 63;
    const int wv = tid >> 6;           // wave 0..3
    const int wm = wv >> 1, wn = wv & 1;
    const int fr = lane & 15;          // row/col within 16x16 fragment
    const int kg = lane >> 4;          // k-group 0..3

    // A staging: thread handles 16 consecutive K elems of one row
    const int srow = tid >> 1;
    const int oh   = tid & 1;
    const bool a_ok = (m0 + srow) < M;
    const float* Ap = A + (size_t)(m0 + srow) * K + oh * 16;

    // swizzled LDS write positions for A (u16 units)
    const int swc = (srow >> 1) & 3;
    const int p0 = srow * 32 + ((((oh << 1) + 0) ^ swc) << 3);
    const int p1 = srow * 32 + ((((oh << 1) + 1) ^ swc) << 3);
    // swizzled read chunk (row bits 1..2 come from fr for all fragment rows)
    const int rdc = (kg ^ ((fr >> 1) & 3)) << 3;

    // B staging: per plane, wave wv copies slots {wv, wv+4}; slot s = 512 u16.
    const int KBLK = K >> 5;
    const size_t btile0 = ((size_t)(n0 >> 7) * KBLK) << 12;  // *4096 u16 per tile
    const int bso0 = wv * 512 + lane * 8;
    const int bso1 = (wv + 4) * 512 + lane * 8;

    f32x4 acc[4][4] = {};

    const int nt = K >> 5;
    for (int t = 0; t < nt; ++t) {
        __syncthreads();  // barrier 1: previous compute done reading LDS

        // ---- stage phase ----
        {
            const int k0 = t << 5;
            float ar[16];
            if (a_ok) {
                float4 v;
                v = *(const float4*)(Ap + k0);      ar[0]=v.x;  ar[1]=v.y;  ar[2]=v.z;  ar[3]=v.w;
                v = *(const float4*)(Ap + k0 + 4);  ar[4]=v.x;  ar[5]=v.y;  ar[6]=v.z;  ar[7]=v.w;
                v = *(const float4*)(Ap + k0 + 8);  ar[8]=v.x;  ar[9]=v.y;  ar[10]=v.z; ar[11]=v.w;
                v = *(const float4*)(Ap + k0 + 12); ar[12]=v.x; ar[13]=v.y; ar[14]=v.z; ar[15]=v.w;
            } else {
#pragma unroll
                for (int c = 0; c < 16; ++c) ar[c] = 0.f;
            }
            const u16* bt = Bth + btile0 + ((size_t)t << 12);
            const u16* blt = Btl + btile0 + ((size_t)t << 12);
            uint4 bh0 = *(const uint4*)(bt + bso0);
            uint4 bh1 = *(const uint4*)(bt + bso1);
            uint4 bl0 = *(const uint4*)(blt + bso0);
            uint4 bl1 = *(const uint4*)(blt + bso1);

            unsigned hw[8], lw[8];
#pragma unroll
            for (int c = 0; c < 8; ++c) {
                // truncation split: a = hi + lo + eps, |eps| <= 2^-16 |a|
                unsigned u0 = __float_as_uint(ar[2 * c]);
                unsigned h0 = u0 >> 16;
                float r0 = ar[2 * c] - __uint_as_float(h0 << 16);
                unsigned l0 = __float_as_uint(r0) >> 16;
                unsigned u1 = __float_as_uint(ar[2 * c + 1]);
                unsigned h1 = u1 >> 16;
                float r1 = ar[2 * c + 1] - __uint_as_float(h1 << 16);
                unsigned l1 = __float_as_uint(r1) >> 16;
                hw[c] = h0 | (h1 << 16);
                lw[c] = l0 | (l1 << 16);
            }
            u16* ahp = &Ah[0][0];
            u16* alp = &Al[0][0];
            *(uint4*)&ahp[p0] = make_uint4(hw[0], hw[1], hw[2], hw[3]);
            *(uint4*)&ahp[p1] = make_uint4(hw[4], hw[5], hw[6], hw[7]);
            *(uint4*)&alp[p0] = make_uint4(lw[0], lw[1], lw[2], lw[3]);
            *(uint4*)&alp[p1] = make_uint4(lw[4], lw[5], lw[6], lw[7]);
            u16* bhp = &Bh[0][0];
            u16* blp = &Bl[0][0];
            *(uint4*)&bhp[bso0] = bh0;
            *(uint4*)&bhp[bso1] = bh1;
            *(uint4*)&blp[bso0] = bl0;
            *(uint4*)&blp[bso1] = bl1;
        }

        __syncthreads();  // barrier 2: stores visible

        // ---- compute phase ----
        bf16x8 afh[4], afl[4], bfh[4], bfl[4];
#pragma unroll
        for (int i = 0; i < 4; ++i) {
            const int aoff = (wm * 64 + i * 16 + fr) * 32 + rdc;
            const int boff = (wn * 64 + i * 16 + fr) * 32 + rdc;
            afh[i] = *(const bf16x8*)&Ah[0][aoff];
            afl[i] = *(const bf16x8*)&Al[0][aoff];
            bfh[i] = *(const bf16x8*)&Bh[0][boff];
            bfl[i] = *(const bf16x8*)&Bl[0][boff];
        }
#pragma unroll
        for (int i = 0; i < 4; ++i)
#pragma unroll
            for (int j = 0; j < 4; ++j) {
                acc[i][j] = __builtin_amdgcn_mfma_f32_16x16x32_bf16(afh[i], bfh[j], acc[i][j], 0, 0, 0);
                acc[i][j] = __builtin_amdgcn_mfma_f32_16x16x32_bf16(afl[i], bfh[j], acc[i][j], 0, 0, 0);
                acc[i][j] = __builtin_amdgcn_mfma_f32_16x16x32_bf16(afh[i], bfl[j], acc[i][j], 0, 0, 0);
            }
    }

    // C/D layout (m89/m91-verified): col = lane&15, row = (lane>>4)*4 + reg
    if (!SCORE) {
#pragma unroll
        for (int j = 0; j < 4; ++j) {
            const int col = n0 + wn * 64 + j * 16 + fr;
            const float bj = bias[col];
#pragma unroll
            for (int i = 0; i < 4; ++i) {
                const int rbase = m0 + wm * 64 + i * 16 + kg * 4;
#pragma unroll
                for (int r = 0; r < 4; ++r) {
                    const int grow = rbase + r;
                    if (grow < M) C[(size_t)grow * N + col] = acc[i][j][r] + bj;
                }
            }
        }
    } else {
        float ssum = 0.f;
#pragma unroll
        for (int j = 0; j < 4; ++j) {
            const int col = n0 + wn * 64 + j * 16 + fr;
            const float bj = bias[col];
            const float qj = qv[col];
#pragma unroll
            for (int i = 0; i < 4; ++i) {
                const int rbase = m0 + wm * 64 + i * 16 + kg * 4;
#pragma unroll
                for (int r = 0; r < 4; ++r) {
                    if (rbase + r < M) ssum += tanhf(acc[i][j][r] + bj) * qj;
                }
            }
        }
#pragma unroll
        for (int o = 32; o; o >>= 1) ssum += __shfl_xor(ssum, o);
        __syncthreads();  // all waves done with LDS before reuse for reduction
        float* red = (float*)&Ah[0][0];
        if (lane == 0) red[wv] = ssum;
        __syncthreads();
        if (tid == 0) atomicAdd(score, red[0] + red[1] + red[2] + red[3]);
    }
}

// ---------------- per-node attention scores: s_i[n] = h[n,:] . v_i ----------------

template <int NV>
__global__ void scores_kernel(const float* __restrict__ h, int n, int D,
                              const float* __restrict__ v0, const float* __restrict__ v1,
                              const float* __restrict__ v2, const float* __restrict__ v3,
                              float* __restrict__ s0, float* __restrict__ s1,
                              float* __restrict__ s2, float* __restrict__ s3)
{
    const int lane = threadIdx.x & 63;
    int wid = (blockIdx.x * blockDim.x + threadIdx.x) >> 6;
    const int nw = (gridDim.x * blockDim.x) >> 6;
    for (int node = wid; node < n; node += nw) {
        const float* row = h + (size_t)node * D;
        float a0 = 0, a1 = 0, a2 = 0, a3 = 0;
        for (int d = lane * 4; d < D; d += 256) {
            float4 x = *(const float4*)&row[d];
            float4 w = *(const float4*)&v0[d];
            a0 += x.x * w.x + x.y * w.y + x.z * w.z + x.w * w.w;
            if (NV > 1) { float4 u = *(const float4*)&v1[d]; a1 += x.x * u.x + x.y * u.y + x.z * u.z + x.w * u.w; }
            if (NV > 2) { float4 u = *(const float4*)&v2[d]; a2 += x.x * u.x + x.y * u.y + x.z * u.z + x.w * u.w; }
            if (NV > 3) { float4 u = *(const float4*)&v3[d]; a3 += x.x * u.x + x.y * u.y + x.z * u.z + x.w * u.w; }
        }
#pragma unroll
        for (int o = 32; o; o >>= 1) {
            a0 += __shfl_xor(a0, o);
            if (NV > 1) a1 += __shfl_xor(a1, o);
            if (NV > 2) a2 += __shfl_xor(a2, o);
            if (NV > 3) a3 += __shfl_xor(a3, o);
        }
        if (lane == 0) {
            s0[node] = a0;
            if (NV > 1) s1[node] = a1;
            if (NV > 2) s2[node] = a2;
            if (NV > 3) s3[node] = a3;
        }
    }
}

// ---------------- edge scalar phases ----------------

__global__ void count_kernel(const void* __restrict__ e, int E, const int* __restrict__ flag,
                             int* __restrict__ cnt) {
    int i = blockIdx.x * blockDim.x + threadIdx.x;
    if (i >= E) return;
    int f = *flag;
    atomicAdd(&cnt[edge_at(e, (size_t)E + i, f)], 1);
}

// wave-shfl scan: 4 barriers per 1024-chunk; writes offs AND cursor (saves a copy pass)
__global__ void scan_kernel(const int* __restrict__ cnt, int n, int* __restrict__ offs,
                            int* __restrict__ cursor) {
    __shared__ int wsum[16];
    __shared__ int carry_s;
    const int t = threadIdx.x;           // 1024 threads = 16 waves
    const int lane = t & 63, w = t >> 6;
    if (t == 0) carry_s = 0;
    __syncthreads();
    for (int base = 0; base < n; base += 1024) {
        int v = (base + t < n) ? cnt[base + t] : 0;
        int x = v;
#pragma unroll
        for (int o = 1; o < 64; o <<= 1) {
            int y = __shfl_up(x, o);
            if (lane >= o) x += y;
        }
        if (lane == 63) wsum[w] = x;
        __syncthreads();
        if (w == 0 && lane < 16) {
            int s = wsum[lane];
#pragma unroll
            for (int o = 1; o < 16; o <<= 1) {
                int y = __shfl_up(s, o);
                if (lane >= o) s += y;
            }
            wsum[lane] = s;  // inclusive wave-sum scan
        }
        __syncthreads();
        const int carry = carry_s;
        const int woff = (w > 0) ? wsum[w - 1] : 0;
        if (base + t < n) {
            int excl = carry + woff + x - v;
            offs[base + t] = excl;
            cursor[base + t] = excl;
        }
        __syncthreads();
        if (t == 1023) carry_s = carry + wsum[15];
        __syncthreads();
    }
    if (t == 0) offs[n] = carry_s;
}

__global__ void scatter_kernel(const void* __restrict__ e, int E, const int* __restrict__ flag,
                               int* __restrict__ cursor, int* __restrict__ eids) {
    int i = blockIdx.x * blockDim.x + threadIdx.x;
    if (i >= E) return;
    int f = *flag;
    int dst = edge_at(e, (size_t)E + i, f);
    int slot = atomicAdd(&cursor[dst], 1);
    eids[slot] = i;
}

__global__ void edge_alpha_max_kernel(const void* __restrict__ e, int E, const int* __restrict__ flag,
                                      const float* __restrict__ ssrc, const float* __restrict__ sdst,
                                      float* __restrict__ alpha, unsigned* __restrict__ mmono) {
    int i = blockIdx.x * blockDim.x + threadIdx.x;
    if (i >= E) return;
    int f = *flag;
    int s = edge_at(e, i, f);
    int d = edge_at(e, (size_t)E + i, f);
    float a = ssrc[s] + sdst[d];
    a = (a >= 0.f) ? a : 0.2f * a;  // leaky_relu 0.2
    alpha[i] = a;
    atomicMax(&mmono[d], f2mono(a));
}

__global__ void edge_exp_sum_kernel(const void* __restrict__ e, int E, const int* __restrict__ flag,
                                    const unsigned* __restrict__ mmono,
                                    float* __restrict__ alpha_ev, float* __restrict__ denom) {
    int i = blockIdx.x * blockDim.x + threadIdx.x;
    if (i >= E) return;
    int f = *flag;
    int d = edge_at(e, (size_t)E + i, f);
    float m = mono2f(mmono[d]);
    float ev = expf(alpha_ev[i] - m);
    alpha_ev[i] = ev;
    atomicAdd(&denom[d], ev);
}

// ---------------- CSR aggregation: out[dst,:] = relu( sum_e w_e * h_src[src_e,:] ) --
// 4-wide edge batching: 4 rows' loads in flight per lane -> 4x memory-level
// parallelism on the latency-bound gather path.

template <int DW>  // floats per lane: D/64
__global__ __launch_bounds__(256) void agg_kernel(
    const int* __restrict__ offs, const int* __restrict__ eids,
    const void* __restrict__ e, const int* __restrict__ flag,
    const float* __restrict__ ev, const float* __restrict__ denom,
    const float* __restrict__ hsrc, float* __restrict__ out,
    int n_dst, int E, int D)
{
    const int lane = threadIdx.x & 63;
    int wid = (blockIdx.x * blockDim.x + threadIdx.x) >> 6;
    const int nw = (gridDim.x * blockDim.x) >> 6;
    const int f = *flag;
    for (int dst = wid; dst < n_dst; dst += nw) {
        const int beg = offs[dst], end = offs[dst + 1];
        float acc[DW] = {};
        const float rden = (end > beg) ? 1.f / denom[dst] : 0.f;
        int j = beg;
        for (; j + 4 <= end; j += 4) {
            const int e0 = eids[j], e1 = eids[j + 1], e2 = eids[j + 2], e3 = eids[j + 3];
            const float w0 = ev[e0] * rden, w1 = ev[e1] * rden;
            const float w2 = ev[e2] * rden, w3 = ev[e3] * rden;
            const float* r0 = hsrc + (size_t)edge_at(e, e0, f) * D + lane * DW;
            const float* r1 = hsrc + (size_t)edge_at(e, e1, f) * D + lane * DW;
            const float* r2 = hsrc + (size_t)edge_at(e, e2, f) * D + lane * DW;
            const float* r3 = hsrc + (size_t)edge_at(e, e3, f) * D + lane * DW;
#pragma unroll
            for (int c = 0; c < DW; c += 4) {
                float4 a0 = *(const float4*)&r0[c];
                float4 a1 = *(const float4*)&r1[c];
                float4 a2 = *(const float4*)&r2[c];
                float4 a3 = *(const float4*)&r3[c];
                acc[c + 0] += a0.x * w0 + a1.x * w1 + a2.x * w2 + a3.x * w3;
                acc[c + 1] += a0.y * w0 + a1.y * w1 + a2.y * w2 + a3.y * w3;
                acc[c + 2] += a0.z * w0 + a1.z * w1 + a2.z * w2 + a3.z * w3;
                acc[c + 3] += a0.w * w0 + a1.w * w1 + a2.w * w2 + a3.w * w3;
            }
        }
        for (; j < end; ++j) {
            const int eid = eids[j];
            const float w = ev[eid] * rden;
            const float* row = hsrc + (size_t)edge_at(e, eid, f) * D + lane * DW;
#pragma unroll
            for (int c = 0; c < DW; c += 4) {
                float4 v = *(const float4*)&row[c];
                acc[c + 0] += v.x * w; acc[c + 1] += v.y * w;
                acc[c + 2] += v.z * w; acc[c + 3] += v.w * w;
            }
        }
        float* orow = out + (size_t)dst * D + lane * DW;
#pragma unroll
        for (int c = 0; c < DW; c += 4) {
            float4 v = make_float4(fmaxf(acc[c + 0], 0.f), fmaxf(acc[c + 1], 0.f),
                                   fmaxf(acc[c + 2], 0.f), fmaxf(acc[c + 3], 0.f));
            *(float4*)&orow[c] = v;
        }
    }
}

// ---------------- semantic attention tail ----------------

__global__ void softmax2_kernel(const float* __restrict__ score, float invN, float* __restrict__ w) {
    if (threadIdx.x == 0 && blockIdx.x == 0) {
        float s0 = score[0] * invN, s1 = score[1] * invN;
        float m = fmaxf(s0, s1);
        float e0 = expf(s0 - m), e1 = expf(s1 - m);
        float r = 1.f / (e0 + e1);
        w[0] = e0 * r;
        w[1] = e1 * r;
    }
}

__global__ void combine2_kernel(const float4* __restrict__ a, const float4* __restrict__ b,
                                const float* __restrict__ w, float4* __restrict__ o, int n4) {
    float w0 = w[0], w1 = w[1];
    for (int i = blockIdx.x * blockDim.x + threadIdx.x; i < n4; i += gridDim.x * blockDim.x) {
        float4 x = a[i], y = b[i];
        o[i] = make_float4(w0 * x.x + w1 * y.x, w0 * x.y + w1 * y.y,
                           w0 * x.z + w1 * y.z, w0 * x.w + w1 * y.w);
    }
}

// ---------------- host orchestration ----------------

extern "C" void kernel_launch(void* const* d_in, const int* in_sizes, int n_in,
                              void* d_out, int out_size, void* d_ws, size_t ws_size,
                              hipStream_t stream) {
    const float* x_a  = (const float*)d_in[0];
    const float* x_p  = (const float*)d_in[1];
    const float* W1   = (const float*)d_in[2];
    const float* b1   = (const float*)d_in[3];
    const float* att1 = (const float*)d_in[4];
    const float* kW1  = (const float*)d_in[5];
    const float* kb1  = (const float*)d_in[6];
    const float* q1   = (const float*)d_in[7];
    const float* W2   = (const float*)d_in[8];
    const float* b2   = (const float*)d_in[9];
    const float* att2 = (const float*)d_in[10];
    const float* kW2  = (const float*)d_in[11];
    const float* kb2  = (const float*)d_in[12];
    const float* q2   = (const float*)d_in[13];
    const void* e_ap  = d_in[14];
    const void* e_pa  = d_in[15];
    const void* e_aa  = d_in[16];
    float* out = (float*)d_out;

    size_t off = 0;
    auto ALLOC = [&](size_t nbytes) -> void* {
        void* p = (char*)d_ws + off;
        off += (nbytes + 255) & ~(size_t)255;
        return p;
    };
    float* bufA = (float*)ALLOC((size_t)NPAP * DHID * 4);  // h_p -> out_p(x2_p)
    float* bufB = (float*)ALLOC((size_t)NA * DHID * 4);    // h_a -> h2_p
    float* bufC = (float*)ALLOC((size_t)NA * DHID * 4);    // out_a1 -> x2_a -> oa1_2|oa2_2
    float* bufD = (float*)ALLOC((size_t)NA * DHID * 4);    // out_a2 -> h2_a
    float* sa_w  = (float*)ALLOC((size_t)NA * 4);
    float* sa_pd = (float*)ALLOC((size_t)NA * 4);
    float* sa_as = (float*)ALLOC((size_t)NA * 4);
    float* sa_ad = (float*)ALLOC((size_t)NA * 4);
    float* sp_wd = (float*)ALLOC((size_t)NPAP * 4);
    float* sp_ps = (float*)ALLOC((size_t)NPAP * 4);
    float* alphab = (float*)ALLOC((size_t)EAP * 4);
    unsigned* mmono = (unsigned*)ALLOC((size_t)NPAP * 4);
    float* denom = (float*)ALLOC((size_t)NPAP * 4);
    int* cnt    = (int*)ALLOC((size_t)(NPAP + 1) * 4);
    int* cursor = (int*)ALLOC((size_t)(NPAP + 1) * 4);
    int* offs_ap = (int*)ALLOC((size_t)(NPAP + 1) * 4);
    int* offs_pa = (int*)ALLOC((size_t)(NA + 1) * 4);
    int* offs_aa = (int*)ALLOC((size_t)(NA + 1) * 4);
    int* eids_ap = (int*)ALLOC((size_t)EAP * 4);
    int* eids_pa = (int*)ALLOC((size_t)EPA * 4);
    int* eids_aa = (int*)ALLOC((size_t)EAA * 4);
    float* score = (float*)ALLOC(8 * 4);
    float* wsem  = (float*)ALLOC(2 * 4);
    int* eflag   = (int*)ALLOC(4);
    if (off > ws_size) return;  // insufficient scratch -> visible failure

    // bth/btl (512KB each) alias alphab (1.6MB): alphab is only live inside an
    // edge_attn phase; no GEMM runs between its producer and consumers (stream order).
    u16* bth = (u16*)alphab;
    u16* btl = bth + 512 * 512;

    hipStream_t s = stream;

    detect_kernel<<<1, 256, 0, s>>>((const unsigned*)e_ap, 1024, eflag);

    auto build_csr = [&](const void* ei, int E, int ndst, int* offs, int* eids) {
        int gn = (ndst + 255) / 256;
        int ge = (E + 255) / 256;
        fill_u32_kernel<<<gn, 256, 0, s>>>((unsigned*)cnt, 0u, ndst);
        count_kernel<<<ge, 256, 0, s>>>(ei, E, eflag, cnt);
        scan_kernel<<<1, 1024, 0, s>>>(cnt, ndst, offs, cursor);
        scatter_kernel<<<ge, 256, 0, s>>>(ei, E, eflag, cursor, eids);
    };
    build_csr(e_ap, EAP, NPAP, offs_ap, eids_ap);
    build_csr(e_pa, EPA, NA, offs_pa, eids_pa);
    build_csr(e_aa, EAA, NA, offs_aa, eids_aa);

    auto gemm = [&](const float* A_, const float* B_, const float* bias_, float* C_,
                    int M, int N, int K, const float* qv, float* sc) {
        conv_bt_kernel<<<dim3(N / 32, K / 32), dim3(32, 8), 0, s>>>(B_, bth, btl, K, N);
        int gx = N / 128;
        int gy = (M + 127) / 128;
        int nwg = gx * gy;
        if (qv)
            mfma_gemm_kernel<true><<<nwg, 256, 0, s>>>(A_, bth, btl, bias_, nullptr, M, N, K, qv, sc, gx);
        else
            mfma_gemm_kernel<false><<<nwg, 256, 0, s>>>(A_, bth, btl, bias_, C_, M, N, K, nullptr, nullptr, gx);
    };

    auto edge_attn = [&](const void* ei, int E, int ndst, const float* ssrc, const float* sdst_,
                         const int* offs, const int* eids, const float* hsrc, float* outp, int D) {
        int gn = (ndst + 255) / 256;
        int ge = (E + 255) / 256;
        fill2_kernel<<<gn, 256, 0, s>>>(mmono, MONO_NEG_INF, (unsigned*)denom, 0u, ndst);
        edge_alpha_max_kernel<<<ge, 256, 0, s>>>(ei, E, eflag, ssrc, sdst_, alphab, mmono);
        edge_exp_sum_kernel<<<ge, 256, 0, s>>>(ei, E, eflag, mmono, alphab, denom);
        int gw = (ndst + 3) / 4;
        if (D == 512)
            agg_kernel<8><<<gw, 256, 0, s>>>(offs, eids, ei, eflag, alphab, denom, hsrc, outp, ndst, E, D);
        else
            agg_kernel<4><<<gw, 256, 0, s>>>(offs, eids, ei, eflag, alphab, denom, hsrc, outp, ndst, E, D);
    };

    auto semantic = [&](const float* o1, const float* o2, const float* kW, const float* kb,
                        const float* q, int D, float* dst) {
        fill_u32_kernel<<<1, 64, 0, s>>>((unsigned*)score, 0u, 2);
        gemm(o1, kW, kb, nullptr, NA, D, D, q, &score[0]);
        gemm(o2, kW, kb, nullptr, NA, D, D, q, &score[1]);
        softmax2_kernel<<<1, 64, 0, s>>>(score, 1.f / (float)NA, wsem);
        combine2_kernel<<<2048, 256, 0, s>>>((const float4*)o1, (const float4*)o2, wsem,
                                             (float4*)dst, NA * D / 4);
    };

    // ---------------- layer 1 (D = 512) ----------------
    float* h_a = bufB;
    float* h_p = bufA;
    gemm(x_a, W1, b1, h_a, NA, DHID, DIN, nullptr, nullptr);
    gemm(x_p, W1 + (size_t)DIN * DHID, b1 + DHID, h_p, NPAP, DHID, DIN, nullptr, nullptr);

    {
        int ga = (NA + 3) / 4 < 4096 ? (NA + 3) / 4 : 4096;
        int gp = (NPAP + 3) / 4 < 4096 ? (NPAP + 3) / 4 : 4096;
        scores_kernel<4><<<ga, 256, 0, s>>>(h_a, NA, DHID,
            att1 + 0 * DHID, att1 + 3 * DHID, att1 + 4 * DHID, att1 + 5 * DHID,
            sa_w, sa_pd, sa_as, sa_ad);
        scores_kernel<2><<<gp, 256, 0, s>>>(h_p, NPAP, DHID,
            att1 + 1 * DHID, att1 + 2 * DHID, nullptr, nullptr,
            sp_wd, sp_ps, nullptr, nullptr);
    }

    edge_attn(e_pa, EPA, NA, sp_ps, sa_pd, offs_pa, eids_pa, h_p, bufC, DHID);  // out_a1
    edge_attn(e_aa, EAA, NA, sa_as, sa_ad, offs_aa, eids_aa, h_a, bufD, DHID);  // out_a2
    edge_attn(e_ap, EAP, NPAP, sa_w, sp_wd, offs_ap, eids_ap, h_a, bufA, DHID); // out_p

    semantic(bufC, bufD, kW1, kb1, q1, DHID, bufC);  // x2_a in bufC; x2_p = bufA

    // ---------------- layer 2 (D = 256) ----------------
    float* h2a = bufD;
    float* h2p = bufB;
    gemm(bufC, W2, b2, h2a, NA, DOUT, DHID, nullptr, nullptr);
    gemm(bufA, W2 + (size_t)DHID * DOUT, b2 + DOUT, h2p, NPAP, DOUT, DHID, nullptr, nullptr);

    {
        int ga = (NA + 3) / 4 < 4096 ? (NA + 3) / 4 : 4096;
        int gp = (NPAP + 3) / 4 < 4096 ? (NPAP + 3) / 4 : 4096;
        scores_kernel<3><<<ga, 256, 0, s>>>(h2a, NA, DOUT,
            att2 + 3 * DOUT, att2 + 4 * DOUT, att2 + 5 * DOUT, nullptr,
            sa_pd, sa_as, sa_ad, nullptr);
        scores_kernel<1><<<gp, 256, 0, s>>>(h2p, NPAP, DOUT,
            att2 + 2 * DOUT, nullptr, nullptr, nullptr,
            sp_ps, nullptr, nullptr, nullptr);
    }

    float* oa1 = bufC;
    float* oa2 = bufC + (size_t)NA * DOUT;
    edge_attn(e_pa, EPA, NA, sp_ps, sa_pd, offs_pa, eids_pa, h2p, oa1, DOUT);
    edge_attn(e_aa, EAA, NA, sa_as, sa_ad, offs_aa, eids_aa, h2a, oa2, DOUT);

    semantic(oa1, oa2, kW2, kb2, q2, DOUT, out);
}